// Round 7
// baseline (176.853 us; speedup 1.0000x reference)
//
#include <hip/hip_runtime.h>

#define NKNOT 225     // table knots, spacing 5/224
#define KBIN 224      // interpolation bins
#define TSTRIDE 68    // packed-table row stride in uints
#define FBASE 15232   // uint index of f-chunk region (= KBIN*TSTRIDE)
#define NWG 256

typedef _Float16 half2v __attribute__((ext_vector_type(2)));

__device__ __forceinline__ float ssp(float x) {
    return fmaxf(x, 0.0f) + log1pf(expf(-fabsf(x))) - 0.69314718055994531f;
}

__device__ __forceinline__ float bclane(float v, int l) {
    return __builtin_bit_cast(float, __builtin_amdgcn_readlane(__builtin_bit_cast(int, v), l));
}

// out[lane] = sum_f bclane(x,f) * WT[lane][f]; WT swizzled, b128 conflict-free
__device__ __forceinline__ float matvec64(const float* __restrict__ ldsA, int base, float xv, int lane) {
    float a0 = 0.f, a1 = 0.f, a2 = 0.f, a3 = 0.f;
    #pragma unroll
    for (int gg = 0; gg < 16; ++gg) {
        const float4 w = *(const float4*)&ldsA[base + lane*64 + (((gg + lane) & 15) << 2)];
        a0 += bclane(xv, gg*4+0) * w.x;
        a1 += bclane(xv, gg*4+1) * w.y;
        a2 += bclane(xv, gg*4+2) * w.z;
        a3 += bclane(xv, gg*4+3) * w.w;
    }
    return (a0 + a1) + (a2 + a3);
}

__device__ __forceinline__ void stageWT(float* __restrict__ lds, int base, const float* __restrict__ W, int tid) {
    for (int s = tid; s < 4096; s += 512) {
        int f = s >> 6, g = s & 63;
        lds[base + g*64 + ((((f >> 2) + g) & 15) << 2) + (f & 3)] = W[s];
    }
}

// fast grid barrier: one counter slot per use; cooperative launch guarantees residency
__device__ __forceinline__ void gbar(int* cnt, int slot, int tid) {
    __syncthreads();
    if (tid == 0) {
        __hip_atomic_fetch_add(&cnt[slot], 1, __ATOMIC_ACQ_REL, __HIP_MEMORY_SCOPE_AGENT);
        while (__hip_atomic_load(&cnt[slot], __ATOMIC_ACQUIRE, __HIP_MEMORY_SCOPE_AGENT) < NWG)
            __builtin_amdgcn_s_sleep(8);
    }
    __syncthreads();
}

__global__ void zero_cnt(int* cnt) {
    if (threadIdx.x < 8) cnt[threadIdx.x] = 0;
}

__global__ __launch_bounds__(512) void schnet_fused(
    const float* __restrict__ emb, const float* __restrict__ dists,
    const float* __restrict__ in2f,
    const float* __restrict__ fw1, const float* __restrict__ fb1,
    const float* __restrict__ fw2, const float* __restrict__ fb2,
    const float* __restrict__ f2o, const float* __restrict__ f2b,
    const float* __restrict__ dw,  const float* __restrict__ db,
    const float* __restrict__ aw1, const float* __restrict__ ab1,
    const float* __restrict__ aw2, const float* __restrict__ ab2,
    float* __restrict__ out,
    float* __restrict__ T_ws, unsigned short* __restrict__ f16w,
    float* __restrict__ x_buf, float* __restrict__ y_ws, int* __restrict__ cnt)
{
    __shared__ unsigned int ldsu[FBASE + 4096];   // 77312 B, aliased by all phases
    float* lds = (float*)ldsu;
    const int wg = blockIdx.x, tid = threadIdx.x;
    const int wave = tid >> 6, lane = tid & 63;
    const int jc = wg & 3, it = (wg >> 2) & 15, b = wg >> 6;
    const int i0 = it * 32;
    const int row = wg*8 + wave;
    const size_t ro = (size_t)row*64 + lane;

    // ================= P0: f0 = emb@in2f for own rows; wgs 0..86 also build tables =================
    stageWT(lds, 0, in2f, tid);
    const bool tabwg = (wg < 87);
    const int tt = wg / 29;
    if (tabwg) {
        const float* fw1t = fw1 + tt*25*64;
        const float* fw2t = fw2 + tt*64*64;
        for (int s = tid; s < 1600; s += 512) lds[4096 + s] = fw1t[s];
        for (int s = tid; s < 4096; s += 512) lds[5696 + s] = fw2t[s];
        if (tid < 64) { lds[9792 + tid] = fb1[tt*64 + tid]; lds[9856 + tid] = fb2[tt*64 + tid]; }
    }
    __syncthreads();
    {
        float xv = emb[ro];
        float fo = matvec64(lds, 0, xv, lane);
        f16w[ro] = __builtin_bit_cast(unsigned short, (_Float16)fo);
    }
    if (tabwg) {
        int k = (wg % 29)*8 + wave;
        if (k < NKNOT) {
            float dk = (float)k * (5.0f/224.0f);
            float h1 = lds[9792 + lane];
            for (int r = 0; r < 25; ++r) {
                float sr = dk - (float)r * (5.0f/24.0f);
                h1 += expf(-10.0f*sr*sr) * lds[4096 + r*64 + lane];
            }
            float u = ssp(h1);
            float T = lds[9856 + lane];
            #pragma unroll
            for (int gg = 0; gg < 64; ++gg)
                T += bclane(u, gg) * lds[5696 + gg*64 + lane];
            T_ws[((size_t)tt*NKNOT + k)*64 + lane] = T;
        }
    }
    gbar(cnt, 0, tid);

    // ================= 3 blocks: conv then pre/final =================
    for (int t = 0; t < 3; ++t) {
        // ---- conv phase ----
        const float* Tt = T_ws + (size_t)t*NKNOT*64;
        for (int e = tid; e < KBIN*16; e += 512) {      // pack f16 [T|dT], stride-68 rows
            int k = e >> 4, fq = e & 15;
            float4 A = *(const float4*)&Tt[k*64 + fq*4];
            float4 Bv = *(const float4*)&Tt[(k+1)*64 + fq*4];
            half2v t01 = { (_Float16)A.x, (_Float16)A.y };
            half2v t23 = { (_Float16)A.z, (_Float16)A.w };
            half2v d01 = { (_Float16)(Bv.x - A.x), (_Float16)(Bv.y - A.y) };
            half2v d23 = { (_Float16)(Bv.z - A.z), (_Float16)(Bv.w - A.w) };
            uint4 o;
            o.x = __builtin_bit_cast(unsigned int, t01);
            o.y = __builtin_bit_cast(unsigned int, t23);
            o.z = __builtin_bit_cast(unsigned int, d01);
            o.w = __builtin_bit_cast(unsigned int, d23);
            *(uint4*)&ldsu[k*TSTRIDE + fq*4] = o;
        }
        for (int s = tid; s < 2048; s += 512) {          // transposed f16 f-chunk (128 j)
            int j = s >> 4, fq = s & 15;
            const unsigned int* src = (const unsigned int*)&f16w[((size_t)b*512 + jc*128 + j)*64 + fq*4];
            int jp = j >> 1;
            unsigned int* dst = &ldsu[FBASE + fq*256 + (((jp + fq) & 63) << 2) + (j & 1)*2];
            dst[0] = src[0]; dst[1] = src[1];
        }
        __syncthreads();
        {
            int g = lane >> 4, fq = lane & 15;
            int il = wave*4 + g;                 // 0..31
            const float* drow = &dists[((size_t)(b*512 + i0 + il))*512 + jc*128];
            const unsigned int* Tbase = ldsu + fq*4;
            const unsigned int* ftb = ldsu + FBASE + fq*256;
            const float scale = 224.0f/5.0f;
            float a0 = 0.f, a1 = 0.f, a2 = 0.f, a3 = 0.f;
            #pragma unroll 2
            for (int j4 = 0; j4 < 32; ++j4) {
                float4 dv = *(const float4*)&drow[j4*4];     // global broadcast load
                int jp0 = j4*2;
                uint4 fA = *(const uint4*)&ftb[(((jp0 + fq) & 63) << 2)];
                uint4 fB = *(const uint4*)&ftb[(((jp0 + 1 + fq) & 63) << 2)];
                float dd[4] = {dv.x, dv.y, dv.z, dv.w};
                unsigned int fl_[8] = {fA.x, fA.y, fA.z, fA.w, fB.x, fB.y, fB.z, fB.w};
                #pragma unroll
                for (int u = 0; u < 4; ++u) {
                    float tv = fminf(fmaxf(dd[u], 0.0f)*scale, 223.999f);
                    int k = (int)tv;
                    float fr = tv - (float)k;
                    uint4 tp = *(const uint4*)&Tbase[k*TSTRIDE];
                    _Float16 ah = (_Float16)fr;
                    half2v av = { ah, ah };
                    half2v W01 = __builtin_bit_cast(half2v, tp.z)*av + __builtin_bit_cast(half2v, tp.x);
                    half2v W23 = __builtin_bit_cast(half2v, tp.w)*av + __builtin_bit_cast(half2v, tp.y);
                    half2v f01 = __builtin_bit_cast(half2v, fl_[u*2]);
                    half2v f23 = __builtin_bit_cast(half2v, fl_[u*2+1]);
                    a0 += (float)W01[0] * (float)f01[0];
                    a1 += (float)W01[1] * (float)f01[1];
                    a2 += (float)W23[0] * (float)f23[0];
                    a3 += (float)W23[1] * (float)f23[1];
                }
            }
            float4 acc; acc.x = a0; acc.y = a1; acc.z = a2; acc.w = a3;
            *(float4*)&y_ws[((size_t)jc*2048 + b*512 + i0 + il)*64 + fq*4] = acc;
        }
        gbar(cnt, 1 + 2*t, tid);

        if (t < 2) {
            // ---- pre(t+1): post-MLP + residual + f ----
            int tn = t + 1;
            stageWT(lds, 0, in2f + tn*4096, tid);
            stageWT(lds, 4096, f2o + t*4096, tid);
            stageWT(lds, 8192, dw + t*4096, tid);
            if (tid < 64) { lds[12288 + tid] = f2b[t*64 + tid]; lds[12352 + tid] = db[t*64 + tid]; }
            __syncthreads();
            float y = y_ws[ro] + y_ws[131072 + ro] + y_ws[262144 + ro] + y_ws[393216 + ro];
            float z = matvec64(lds, 4096, y, lane) + lds[12288 + lane];
            float u = ssp(z);
            float y3 = matvec64(lds, 8192, u, lane) + lds[12352 + lane];
            const float* xin = (tn == 1) ? emb : x_buf;
            float xv = xin[ro] + y3;
            x_buf[ro] = xv;
            float fo = matvec64(lds, 0, xv, lane);
            f16w[ro] = __builtin_bit_cast(unsigned short, (_Float16)fo);
            gbar(cnt, 2 + 2*t, tid);
        }
    }

    // ================= final: post-MLP + residual + readout =================
    stageWT(lds, 0, f2o + 2*4096, tid);
    stageWT(lds, 4096, dw + 2*4096, tid);
    for (int s = tid; s < 4096; s += 512) {   // aw1^T duplicated to 64 rows, swizzled
        int f = s >> 6, r = s & 63;
        lds[8192 + r*64 + ((((f >> 2) + r) & 15) << 2) + (f & 3)] = aw1[f*32 + (r & 31)];
    }
    if (tid < 64) {
        lds[12288 + tid] = f2b[2*64 + tid];
        lds[12352 + tid] = db[2*64 + tid];
        lds[12416 + tid] = ab1[tid & 31];
        lds[12480 + tid] = aw2[tid & 31];
    }
    __syncthreads();
    {
        float y = y_ws[ro] + y_ws[131072 + ro] + y_ws[262144 + ro] + y_ws[393216 + ro];
        float z = matvec64(lds, 0, y, lane) + lds[12288 + lane];
        float u = ssp(z);
        float y3 = matvec64(lds, 4096, u, lane) + lds[12352 + lane];
        float x3 = x_buf[ro] + y3;
        float s1 = matvec64(lds, 8192, x3, lane) + lds[12416 + lane];
        float h = ssp(s1) * lds[12480 + lane];
        float sum = h;
        #pragma unroll
        for (int m = 1; m < 64; m <<= 1)
            sum += __shfl_xor(sum, m, 64);
        if (lane == 0) out[row] = ab2[0] + 0.5f*sum;   // lanes duplicate the 32-dim h twice
    }
}

extern "C" void kernel_launch(void* const* d_in, const int* in_sizes, int n_in,
                              void* d_out, int out_size, void* d_ws, size_t ws_size,
                              hipStream_t stream) {
    const float* emb  = (const float*)d_in[0];
    const float* dist = (const float*)d_in[1];
    const float* in2f = (const float*)d_in[2];
    const float* fw1  = (const float*)d_in[3];
    const float* fb1  = (const float*)d_in[4];
    const float* fw2  = (const float*)d_in[5];
    const float* fb2  = (const float*)d_in[6];
    const float* f2o  = (const float*)d_in[7];
    const float* f2b  = (const float*)d_in[8];
    const float* dwp  = (const float*)d_in[9];
    const float* dbp  = (const float*)d_in[10];
    const float* aw1  = (const float*)d_in[11];
    const float* ab1  = (const float*)d_in[12];
    const float* aw2  = (const float*)d_in[13];
    const float* ab2  = (const float*)d_in[14];
    float* out = (float*)d_out;
    float* ws = (float*)d_ws;
    float* T_ws = ws;                                      // 3*225*64 = 43200 (pad 43264)
    unsigned short* f16w = (unsigned short*)(ws + 43264);  // 2048*64 f16 = 65536 float slots
    float* x_buf = ws + 43264 + 65536;                     // 131072 floats
    float* y_ws  = x_buf + 131072;                         // 4*2048*64 = 524288 floats
    int*   cnt   = (int*)(y_ws + 524288);                  // 8 barrier slots

    hipLaunchKernelGGL(zero_cnt, dim3(1), dim3(64), 0, stream, cnt);

    void* args[] = { (void*)&emb, (void*)&dist, (void*)&in2f,
                     (void*)&fw1, (void*)&fb1, (void*)&fw2, (void*)&fb2,
                     (void*)&f2o, (void*)&f2b, (void*)&dwp, (void*)&dbp,
                     (void*)&aw1, (void*)&ab1, (void*)&aw2, (void*)&ab2,
                     (void*)&out, (void*)&T_ws, (void*)&f16w, (void*)&x_buf,
                     (void*)&y_ws, (void*)&cnt };
    hipLaunchCooperativeKernel((const void*)schnet_fused, dim3(NWG), dim3(512), args, 0, stream);
}

// Round 8
// 82.163 us; speedup vs baseline: 2.1525x; 2.1525x over previous
//
#include <hip/hip_runtime.h>

#define NKNOT 225
#define KBIN 224      // interpolation bins
#define TSTRIDE 68    // packed-table row stride in uints
#define TPSZ  15232   // uints per packed table (= KBIN*TSTRIDE)
#define FBASE 15232   // uint index of f-chunk region in conv LDS

typedef _Float16 half2v __attribute__((ext_vector_type(2)));

__device__ __forceinline__ float ssp(float x) {
    // softplus(x) - ln2, numerically stable
    return fmaxf(x, 0.0f) + log1pf(expf(-fabsf(x))) - 0.69314718055994531f;
}

__device__ __forceinline__ float bclane(float v, int l) {
    return __builtin_bit_cast(float, __builtin_amdgcn_readlane(__builtin_bit_cast(int, v), l));
}

// out[lane] = sum_f bclane(x,f) * WT[lane][f]; WT swizzled, b128 conflict-free
__device__ __forceinline__ float matvec64(const float* __restrict__ ldsA, int base, float xv, int lane) {
    float a0 = 0.f, a1 = 0.f, a2 = 0.f, a3 = 0.f;
    #pragma unroll
    for (int gg = 0; gg < 16; ++gg) {
        const float4 w = *(const float4*)&ldsA[base + lane*64 + (((gg + lane) & 15) << 2)];
        a0 += bclane(xv, gg*4+0) * w.x;
        a1 += bclane(xv, gg*4+1) * w.y;
        a2 += bclane(xv, gg*4+2) * w.z;
        a3 += bclane(xv, gg*4+3) * w.w;
    }
    return (a0 + a1) + (a2 + a3);
}

__device__ __forceinline__ void stageWT(float* __restrict__ lds, int base, const float* __restrict__ W, int tid) {
    for (int s = tid; s < 4096; s += 512) {
        int f = s >> 6, g = s & 63;
        lds[base + g*64 + ((((f >> 2) + g) & 15) << 2) + (f & 3)] = W[s];
    }
}

// pre: wgs 0..255: one row per wave — (t>0: post-MLP of prev block + residual) + f = x@in2f -> f16.
//      wgs 256..339 (t==0 only): build + PACK the 3 interp tables (f16 [T|dT], stride-68) to global.
__global__ __launch_bounds__(512) void schnet_pre(
    int t,
    const float* __restrict__ emb,
    float* __restrict__ x_buf,
    const float* __restrict__ y_ws,
    const float* __restrict__ in2f,
    const float* __restrict__ fw1, const float* __restrict__ fb1,
    const float* __restrict__ fw2, const float* __restrict__ fb2,
    const float* __restrict__ f2o, const float* __restrict__ f2b,
    const float* __restrict__ dw,  const float* __restrict__ db,
    unsigned short* __restrict__ f16w, unsigned int* __restrict__ Tp_g)
{
    __shared__ float lds[12544];
    const int wg = blockIdx.x, tid = threadIdx.x;
    const int wave = tid >> 6, lane = tid & 63;
    if (wg < 256) {
        stageWT(lds, 0, in2f + t*4096, tid);
        if (t > 0) {
            stageWT(lds, 4096, f2o + (t-1)*4096, tid);
            stageWT(lds, 8192, dw + (t-1)*4096, tid);
            if (tid < 64) { lds[12288 + tid] = f2b[(t-1)*64 + tid]; lds[12352 + tid] = db[(t-1)*64 + tid]; }
        }
        __syncthreads();
        int row = wg*8 + wave;
        size_t ro = (size_t)row*64 + lane;
        float xv;
        if (t == 0) {
            xv = emb[ro];
        } else {
            float y = 0.0f;
            #pragma unroll
            for (int c = 0; c < 8; ++c) y += y_ws[(size_t)c*131072 + ro];
            float z = matvec64(lds, 4096, y, lane) + lds[12288 + lane];
            float u = ssp(z);
            float y3 = matvec64(lds, 8192, u, lane) + lds[12352 + lane];
            const float* xin = (t == 1) ? emb : x_buf;
            xv = xin[ro] + y3;
            x_buf[ro] = xv;
        }
        float fo = matvec64(lds, 0, xv, lane);
        f16w[ro] = __builtin_bit_cast(unsigned short, (_Float16)fo);
    } else {
        // table build+pack (t==0 launch only): 28 wgs per block tt, 8 bins each
        int widx = wg - 256;
        int tt = widx / 28;
        int k = (widx % 28)*8 + wave;        // bin 0..223
        const float* fw1t = fw1 + tt*25*64;
        const float* fw2t = fw2 + tt*64*64;
        for (int s = tid; s < 1600; s += 512) lds[s] = fw1t[s];
        for (int s = tid; s < 4096; s += 512) lds[1600 + s] = fw2t[s];
        if (tid < 64) { lds[5696 + tid] = fb1[tt*64 + tid]; lds[5760 + tid] = fb2[tt*64 + tid]; }
        __syncthreads();
        float T2[2];
        #pragma unroll
        for (int e = 0; e < 2; ++e) {
            float dk = (float)(k + e) * (5.0f/224.0f);
            float h1 = lds[5696 + lane];
            for (int r = 0; r < 25; ++r) {
                float sr = dk - (float)r * (5.0f/24.0f);
                h1 += expf(-10.0f*sr*sr) * lds[r*64 + lane];
            }
            float u = ssp(h1);
            float T = lds[5760 + lane];
            #pragma unroll
            for (int gg = 0; gg < 64; ++gg)
                T += bclane(u, gg) * lds[1600 + gg*64 + lane];
            T2[e] = T;
        }
        lds[5824 + wave*128 + lane] = T2[0];
        lds[5824 + wave*128 + 64 + lane] = T2[1];
        __syncthreads();
        if (lane < 16) {
            const float* s0 = &lds[5824 + wave*128];
            float4 A  = *(const float4*)&s0[lane*4];
            float4 Bv = *(const float4*)&s0[64 + lane*4];
            half2v t01 = { (_Float16)A.x, (_Float16)A.y };
            half2v t23 = { (_Float16)A.z, (_Float16)A.w };
            half2v d01 = { (_Float16)(Bv.x - A.x), (_Float16)(Bv.y - A.y) };
            half2v d23 = { (_Float16)(Bv.z - A.z), (_Float16)(Bv.w - A.w) };
            uint4 o;
            o.x = __builtin_bit_cast(unsigned int, t01);
            o.y = __builtin_bit_cast(unsigned int, t23);
            o.z = __builtin_bit_cast(unsigned int, d01);
            o.w = __builtin_bit_cast(unsigned int, d23);
            *(uint4*)&Tp_g[(size_t)tt*TPSZ + k*TSTRIDE + lane*4] = o;
        }
    }
}

// conv: y_partial[c8][b*512+i][f] = sum over a 64-j slice of f_j[f] * lerp(T, d_ij)[f]
// 512 wgs: (jc 4) x (it 32) x (b 4); wave covers 2 i's x 2 j-halves. Software-pipelined.
__global__ __launch_bounds__(512, 4) void schnet_conv(
    const float* __restrict__ dists,
    const unsigned short* __restrict__ f16w,
    const unsigned int* __restrict__ Tp,
    float* __restrict__ y_ws)
{
    __shared__ unsigned int ldsu[FBASE + 4096];   // 77312 B -> 2 wgs/CU
    const int wg = blockIdx.x, tid = threadIdx.x;
    const int jc = wg & 3, it = (wg >> 2) & 31, b = wg >> 7;
    const int i0 = it * 16;
    const int wave = tid >> 6, lane = tid & 63;

    // straight copy of pre-packed table (no VALU math)
    for (int s = tid; s < TPSZ/4; s += 512)
        ((uint4*)ldsu)[s] = ((const uint4*)Tp)[s];
    // transposed f16 f-chunk (128 j x 64 f16)
    for (int s = tid; s < 2048; s += 512) {
        int j = s >> 4, fq = s & 15;
        const unsigned int* src = (const unsigned int*)&f16w[((size_t)b*512 + jc*128 + j)*64 + fq*4];
        int jp = j >> 1;
        unsigned int* dst = &ldsu[FBASE + fq*256 + (((jp + fq) & 63) << 2) + (j & 1)*2];
        dst[0] = src[0]; dst[1] = src[1];
    }
    __syncthreads();

    const int g = lane >> 4, fq = lane & 15;
    const int il = wave*2 + (g >> 1);        // 0..15
    const int jh = g & 1;                    // j half
    const float4* drow4 = (const float4*)&dists[((size_t)(b*512 + i0 + il))*512 + jc*128 + jh*64];
    const unsigned int* Tbase = ldsu + fq*4;
    const unsigned int* ftb = ldsu + FBASE + fq*256;
    const float scale = 224.0f/5.0f;

    float a0 = 0.f, a1 = 0.f, a2 = 0.f, a3 = 0.f;
    // pipeline prologue: stage 0 from drow4[0]; dvK = d for next k-stage
    float fr0[4]; uint4 tp0[4];
    {
        float4 dv = drow4[0];
        float dd[4] = {dv.x, dv.y, dv.z, dv.w};
        #pragma unroll
        for (int u = 0; u < 4; ++u) {
            float tv = fminf(fmaxf(dd[u], 0.0f)*scale, 223.999f);
            int k = (int)tv; fr0[u] = tv - (float)k;
            tp0[u] = *(const uint4*)&Tbase[k*TSTRIDE];
        }
    }
    float4 dvK = drow4[1];
    uint4 fA0 = *(const uint4*)&ftb[((jh*32 + 0 + fq) & 63) << 2];
    uint4 fB0 = *(const uint4*)&ftb[((jh*32 + 1 + fq) & 63) << 2];

    #pragma unroll 2
    for (int j4 = 0; j4 < 16; ++j4) {
        // prefetch d two iterations ahead
        float4 dvL = (j4 < 14) ? drow4[j4 + 2] : dvK;
        // stage next iteration's k/fr/T and f
        float fr1[4]; uint4 tp1[4];
        {
            float dd[4] = {dvK.x, dvK.y, dvK.z, dvK.w};
            #pragma unroll
            for (int u = 0; u < 4; ++u) {
                float tv = fminf(fmaxf(dd[u], 0.0f)*scale, 223.999f);
                int k = (int)tv; fr1[u] = tv - (float)k;
                tp1[u] = *(const uint4*)&Tbase[k*TSTRIDE];
            }
        }
        int jpn = jh*32 + ((j4 + 1) & 15)*2;
        uint4 fA1 = *(const uint4*)&ftb[((jpn + fq) & 63) << 2];
        uint4 fB1 = *(const uint4*)&ftb[((jpn + 1 + fq) & 63) << 2];

        // process current stage
        unsigned int fl_[8] = {fA0.x, fA0.y, fA0.z, fA0.w, fB0.x, fB0.y, fB0.z, fB0.w};
        #pragma unroll
        for (int u = 0; u < 4; ++u) {
            _Float16 ah = (_Float16)fr0[u];
            half2v av = { ah, ah };
            half2v W01 = __builtin_bit_cast(half2v, tp0[u].z)*av + __builtin_bit_cast(half2v, tp0[u].x);
            half2v W23 = __builtin_bit_cast(half2v, tp0[u].w)*av + __builtin_bit_cast(half2v, tp0[u].y);
            half2v f01 = __builtin_bit_cast(half2v, fl_[u*2]);
            half2v f23 = __builtin_bit_cast(half2v, fl_[u*2+1]);
            a0 += (float)W01[0] * (float)f01[0];
            a1 += (float)W01[1] * (float)f01[1];
            a2 += (float)W23[0] * (float)f23[0];
            a3 += (float)W23[1] * (float)f23[1];
        }
        // rotate
        dvK = dvL;
        fr0[0]=fr1[0]; fr0[1]=fr1[1]; fr0[2]=fr1[2]; fr0[3]=fr1[3];
        tp0[0]=tp1[0]; tp0[1]=tp1[1]; tp0[2]=tp1[2]; tp0[3]=tp1[3];
        fA0 = fA1; fB0 = fB1;
    }
    int c8 = jc*2 + jh;
    float4 acc; acc.x = a0; acc.y = a1; acc.z = a2; acc.w = a3;
    *(float4*)&y_ws[((size_t)c8*2048 + b*512 + i0 + il)*64 + fq*4] = acc;
}

// final: last post-MLP + residual + readout MLP; one row per wave
__global__ __launch_bounds__(512) void schnet_final(
    const float* __restrict__ x_in,
    const float* __restrict__ y_ws,
    const float* __restrict__ f2o, const float* __restrict__ f2b,
    const float* __restrict__ dw,  const float* __restrict__ db,
    const float* __restrict__ aw1, const float* __restrict__ ab1,
    const float* __restrict__ aw2, const float* __restrict__ ab2,
    float* __restrict__ out)
{
    __shared__ float lds[12544];
    const int wg = blockIdx.x, tid = threadIdx.x;
    const int wave = tid >> 6, lane = tid & 63;
    stageWT(lds, 0, f2o + 2*4096, tid);
    stageWT(lds, 4096, dw + 2*4096, tid);
    for (int s = tid; s < 4096; s += 512) {   // aw1^T duplicated to 64 rows, swizzled
        int f = s >> 6, r = s & 63;
        lds[8192 + r*64 + ((((f >> 2) + r) & 15) << 2) + (f & 3)] = aw1[f*32 + (r & 31)];
    }
    if (tid < 64) {
        lds[12288 + tid] = f2b[2*64 + tid];
        lds[12352 + tid] = db[2*64 + tid];
        lds[12416 + tid] = ab1[tid & 31];
        lds[12480 + tid] = aw2[tid & 31];
    }
    __syncthreads();
    int row = wg*8 + wave;
    size_t ro = (size_t)row*64 + lane;
    float y = 0.0f;
    #pragma unroll
    for (int c = 0; c < 8; ++c) y += y_ws[(size_t)c*131072 + ro];
    float z = matvec64(lds, 0, y, lane) + lds[12288 + lane];
    float u = ssp(z);
    float y3 = matvec64(lds, 4096, u, lane) + lds[12352 + lane];
    float x3 = x_in[ro] + y3;
    float s1 = matvec64(lds, 8192, x3, lane) + lds[12416 + lane];
    float h = ssp(s1) * lds[12480 + lane];
    float sum = h;
    #pragma unroll
    for (int m = 1; m < 64; m <<= 1)
        sum += __shfl_xor(sum, m, 64);
    if (lane == 0) out[row] = ab2[0] + 0.5f*sum;   // lanes duplicate the 32-dim h twice
}

extern "C" void kernel_launch(void* const* d_in, const int* in_sizes, int n_in,
                              void* d_out, int out_size, void* d_ws, size_t ws_size,
                              hipStream_t stream) {
    const float* emb  = (const float*)d_in[0];
    const float* dist = (const float*)d_in[1];
    const float* in2f = (const float*)d_in[2];
    const float* fw1  = (const float*)d_in[3];
    const float* fb1  = (const float*)d_in[4];
    const float* fw2  = (const float*)d_in[5];
    const float* fb2  = (const float*)d_in[6];
    const float* f2o  = (const float*)d_in[7];
    const float* f2b  = (const float*)d_in[8];
    const float* dwp  = (const float*)d_in[9];
    const float* dbp  = (const float*)d_in[10];
    const float* aw1  = (const float*)d_in[11];
    const float* ab1  = (const float*)d_in[12];
    const float* aw2  = (const float*)d_in[13];
    const float* ab2  = (const float*)d_in[14];
    float* out = (float*)d_out;
    float* ws = (float*)d_ws;
    unsigned int* Tp_g = (unsigned int*)ws;                // 3*15232 = 45696 uints
    unsigned short* f16w = (unsigned short*)(ws + 45696);  // 2048*64 f16 = 65536 float slots
    float* x_buf = ws + 45696 + 65536;                     // 131072 floats
    float* y_ws  = x_buf + 131072;                         // 8*2048*64 = 1048576 floats

    for (int t = 0; t < 3; ++t) {
        int grid = (t == 0) ? 340 : 256;   // t=0 carries the 84 table-build/pack wgs
        hipLaunchKernelGGL(schnet_pre, dim3(grid), dim3(512), 0, stream,
            t, emb, x_buf, y_ws, in2f, fw1, fb1, fw2, fb2, f2o, f2b, dwp, dbp, f16w, Tp_g);
        hipLaunchKernelGGL(schnet_conv, dim3(512), dim3(512), 0, stream,
            dist, f16w, Tp_g + (size_t)t*TPSZ, y_ws);
    }
    hipLaunchKernelGGL(schnet_final, dim3(256), dim3(512), 0, stream,
        x_buf, y_ws, f2o, f2b, dwp, dbp, aw1, ab1, aw2, ab2, out);
}